// Round 3
// baseline (1382.874 us; speedup 1.0000x reference)
//
#include <hip/hip_runtime.h>
#include <hip/hip_cooperative_groups.h>
#include <hip/hip_bf16.h>
#include <hip/hip_fp16.h>
#include <stdint.h>

namespace cg = cooperative_groups;

#define D    256   // hidden dim
#define K2   512   // 2*D (GEMM K, q_star width)
#define G4   1024  // 4*D (gate count)
#define B_   1024  // batch (graphs)
#define NBLK 512   // cooperative grid blocks (2/CU -- big validation margin)
#define NTHR 256
#define GSTRIDE (NBLK * NTHR)   // 131072

typedef __attribute__((ext_vector_type(8))) short  short8;
typedef __attribute__((ext_vector_type(4))) float  float4v;

__device__ inline short f2bf(float v) {
    __hip_bfloat16 b = __float2bfloat16(v);
    union { __hip_bfloat16 b; unsigned short u; } cv; cv.b = b;
    return (short)cv.u;
}
__device__ inline float bfs2f(short s) {
    union { unsigned int i; float f; } v;
    v.i = ((unsigned int)(unsigned short)s) << 16;
    return v.f;
}

// ---- wave64 sum via DPP (VALU pipe only) ------------------------------------
__device__ inline float wave_sum64(float x) {
    union { float f; int i; } c, t;
#define DPP_ADD(CTRL, RM)                                                     \
    c.f = x;                                                                  \
    t.i = __builtin_amdgcn_update_dpp(0, c.i, (CTRL), (RM), 0xf, true);       \
    x += t.f;
    DPP_ADD(0x111, 0xf)   // row_shr:1
    DPP_ADD(0x112, 0xf)   // row_shr:2
    DPP_ADD(0x114, 0xf)   // row_shr:4
    DPP_ADD(0x118, 0xf)   // row_shr:8
    DPP_ADD(0x142, 0xa)   // row_bcast:15 -> rows 1,3
    DPP_ADD(0x143, 0xc)   // row_bcast:31 -> rows 2,3
#undef DPP_ADD
    union { float f; int i; } r; r.f = x;
    r.i = __builtin_amdgcn_readlane(r.i, 63);
    return r.f;
}

// =============================================================================
// Cooperative fused kernel: setup + 6 x (GEMM/LSTM -> sync -> attn -> sync)
// grid 512 x 256 (2 blocks/CU), each block: 2 virtual GEMM tiles + 2 graphs.
// =============================================================================
__global__ __launch_bounds__(NTHR, 2) void k_fused(
        const float* __restrict__ feat32, __half* __restrict__ feat16,
        const float* __restrict__ Wih,  const float* __restrict__ Whh,
        const float* __restrict__ bih,  const float* __restrict__ bhh,
        const int* __restrict__ seg, int N,
        short* __restrict__ Wch, short* __restrict__ Wcl,
        float* __restrict__ bsum, int* __restrict__ start,
        short* __restrict__ Xh, short* __restrict__ Xl,
        float* __restrict__ c,  float* __restrict__ h,
        float* __restrict__ X) {
    cg::grid_group grid = cg::this_grid();
    const int b    = blockIdx.x;          // 0..511
    const int t    = threadIdx.x;         // 0..255
    const int gid  = b * NTHR + t;        // 0..131071
    const int lane = t & 63, wave = t >> 6;

    __shared__ float gl[4][16][17];       // GEMM gate tiles (+1 pad)
    __shared__ float accs[4 * D];         // attention wave merge
    __shared__ float ms[4], ls[4];

    // ---------------- phase 0: setup -----------------------------------------
    // zero c, h (B*D = 2*GSTRIDE), Xh, Xl (B*K2 = 4*GSTRIDE)
    c[gid] = 0.f; c[gid + GSTRIDE] = 0.f;
    h[gid] = 0.f; h[gid + GSTRIDE] = 0.f;
#pragma unroll
    for (int i = 0; i < 4; i++) { Xh[gid + i * GSTRIDE] = 0; Xl[gid + i * GSTRIDE] = 0; }
    // weight prep: Wc = [Wih[:, :D] + Whh | Wih[:, D:2D]] split bf16 hi+lo
    for (int idx = gid; idx < G4 * K2; idx += GSTRIDE) {
        int r = idx >> 9, cc = idx & (K2 - 1);
        float v = Wih[idx];
        if (cc < D) v += Whh[r * D + cc];
        short hi = f2bf(v);
        Wch[idx] = hi;
        Wcl[idx] = f2bf(v - bfs2f(hi));
        if (idx < G4) bsum[idx] = bih[idx] + bhh[idx];
    }
    // per-graph boundaries
    if (gid <= B_) {
        int lo = 0, hi = N;
        while (lo < hi) { int mid = (lo + hi) >> 1; if (seg[mid] < gid) lo = mid + 1; else hi = mid; }
        start[gid] = lo;
    }
    // feat fp32 -> fp16
    {
        const int total = N * D;          // multiple of 8
        for (int i = gid * 8; i < total; i += GSTRIDE * 8) {
            float4v a = *(const float4v*)(feat32 + i);
            float4v bb = *(const float4v*)(feat32 + i + 4);
            union { __half2 h2[4]; uint4 u; } o;
            o.h2[0] = __floats2half2_rn(a.x, a.y);
            o.h2[1] = __floats2half2_rn(a.z, a.w);
            o.h2[2] = __floats2half2_rn(bb.x, bb.y);
            o.h2[3] = __floats2half2_rn(bb.z, bb.w);
            *(uint4*)(feat16 + i) = o.u;
        }
    }
    grid.sync();

    for (int it = 0; it < 6; ++it) {
        // ---------------- GEMM + LSTM phase (2 virtual tiles/block) ----------
        for (int vb = b; vb < 1024; vb += NBLK) {
            int row = lane & 15, quad = lane >> 4;
            int m0 = (vb & 63) * 16;
            int jb = (vb >> 6) * 16;               // 0..15 strips of 16 cols
            int wrow = wave * 256 + jb + row;      // W row = gate*256 + column
            const short* pah = Xh  + (size_t)(m0 + row) * K2 + quad * 8;
            const short* pal = Xl  + (size_t)(m0 + row) * K2 + quad * 8;
            const short* pbh = Wch + (size_t)wrow * K2 + quad * 8;
            const short* pbl = Wcl + (size_t)wrow * K2 + quad * 8;
            float4v acc = {0, 0, 0, 0};
#pragma unroll
            for (int k = 0; k < K2; k += 32) {
                short8 ahi = *(const short8*)(pah + k);
                short8 alo = *(const short8*)(pal + k);
                short8 bh  = *(const short8*)(pbh + k);
                short8 bl  = *(const short8*)(pbl + k);
                acc = __builtin_amdgcn_mfma_f32_16x16x32_bf16(ahi, bh, acc, 0, 0, 0);
                acc = __builtin_amdgcn_mfma_f32_16x16x32_bf16(alo, bh, acc, 0, 0, 0);
                acc = __builtin_amdgcn_mfma_f32_16x16x32_bf16(ahi, bl, acc, 0, 0, 0);
            }
#pragma unroll
            for (int i = 0; i < 4; i++) gl[wave][quad * 4 + i][row] = acc[i];
            __syncthreads();
            int mi = t >> 4, jj = t & 15;
            int j = jb + jj;
            float gi = gl[0][mi][jj] + bsum[j];
            float gf = gl[1][mi][jj] + bsum[j + 256];
            float gg = gl[2][mi][jj] + bsum[j + 512];
            float go = gl[3][mi][jj] + bsum[j + 768];
            size_t ix = (size_t)(m0 + mi) * D + j;
            float si = 1.f / (1.f + __expf(-gi));
            float sf = 1.f / (1.f + __expf(-gf));
            float so = 1.f / (1.f + __expf(-go));
            float cn = sf * c[ix] + si * tanhf(gg);
            float hn = so * tanhf(cn);
            c[ix] = cn;
            h[ix] = hn;
            __syncthreads();   // gl reused by next vb
        }
        grid.sync();

        // ---------------- attention phase (2 graphs/block) -------------------
        for (int g = b; g < B_; g += NBLK) {
            float hv = h[(size_t)g * D + t];
            {
                size_t ox = (size_t)g * K2 + t;
                X[ox] = hv;
                short hi = f2bf(hv);
                Xh[ox] = hi;
                Xl[ox] = f2bf(hv - bfs2f(hi));
            }
            int s = start[g], e = start[g + 1];
            s = max(0, min(s, N)); e = max(s, min(e, N));
            int cnt = e - s;
            if (cnt <= 0) {                      // block-uniform branch
                size_t ox = (size_t)g * K2 + D + t;
                X[ox] = 0.f; Xh[ox] = 0; Xl[ox] = 0;
            } else {
                const float NEG = -3.0e38f;
                float4v q = *(const float4v*)(h + (size_t)g * D + lane * 4);
                float m = NEG, l = 0.f;
                float4v acc = {0.f, 0.f, 0.f, 0.f};

                for (int n0 = wave * 4; n0 < cnt; n0 += 16) {
                    uint2 raw[4];
#pragma unroll
                    for (int r = 0; r < 4; r++) {
                        int idx = n0 + r;
                        int ci = (idx < cnt) ? (s + idx) : s;
                        raw[r] = *((const uint2*)(feat16 + (size_t)ci * D) + lane);
                    }
                    float4v rows[4];
                    float ev[4];
#pragma unroll
                    for (int r = 0; r < 4; r++) {
                        union { uint2 u; __half2 h2[2]; } cv; cv.u = raw[r];
                        float2 f01 = __half22float2(cv.h2[0]);
                        float2 f23 = __half22float2(cv.h2[1]);
                        rows[r].x = f01.x; rows[r].y = f01.y;
                        rows[r].z = f23.x; rows[r].w = f23.y;
                        ev[r] = rows[r].x * q.x + rows[r].y * q.y
                              + rows[r].z * q.z + rows[r].w * q.w;
                    }
#pragma unroll
                    for (int r = 0; r < 4; r++) ev[r] = wave_sum64(ev[r]);
                    float mnew = m;
#pragma unroll
                    for (int r = 0; r < 4; r++) {
                        if (n0 + r >= cnt) ev[r] = NEG;
                        mnew = fmaxf(mnew, ev[r]);
                    }
                    float alpha = __expf(m - mnew);
                    float w[4];
                    float wsum = 0.f;
#pragma unroll
                    for (int r = 0; r < 4; r++) {
                        w[r] = (n0 + r < cnt) ? __expf(ev[r] - mnew) : 0.f;
                        wsum += w[r];
                    }
                    l = l * alpha + wsum;
                    acc.x *= alpha; acc.y *= alpha; acc.z *= alpha; acc.w *= alpha;
#pragma unroll
                    for (int r = 0; r < 4; r++) {
                        acc.x += w[r] * rows[r].x;
                        acc.y += w[r] * rows[r].y;
                        acc.z += w[r] * rows[r].z;
                        acc.w += w[r] * rows[r].w;
                    }
                    m = mnew;
                }

                *((float4v*)(accs + wave * D + lane * 4)) = acc;
                if (lane == 0) { ms[wave] = m; ls[wave] = l; }
                __syncthreads();
                float mt = fmaxf(fmaxf(ms[0], ms[1]), fmaxf(ms[2], ms[3]));
                float s0 = __expf(ms[0] - mt), s1 = __expf(ms[1] - mt);
                float s2 = __expf(ms[2] - mt), s3 = __expf(ms[3] - mt);
                float lt = ls[0] * s0 + ls[1] * s1 + ls[2] * s2 + ls[3] * s3;
                float val = (accs[t] * s0 + accs[D + t] * s1
                           + accs[2 * D + t] * s2 + accs[3 * D + t] * s3) / lt;
                size_t ox = (size_t)g * K2 + D + t;
                X[ox] = val;
                short hi = f2bf(val);
                Xh[ox] = hi;
                Xl[ox] = f2bf(val - bfs2f(hi));
            }
            __syncthreads();   // accs/ms/ls reused by next g
        }
        grid.sync();
    }
}

// =============================================================================
// Fallback: proven round-0 multi-kernel pipeline (566 us)
// =============================================================================
__global__ void k_bounds(const int* __restrict__ seg, int N, int B,
                         int* __restrict__ start) {
    int g = blockIdx.x * blockDim.x + threadIdx.x;
    if (g > B) return;
    int lo = 0, hi = N;
    while (lo < hi) { int mid = (lo + hi) >> 1; if (seg[mid] < g) lo = mid + 1; else hi = mid; }
    start[g] = lo;
}

__global__ void k_cvt(const float* __restrict__ feat, __half* __restrict__ feat16,
                      int total) {
    int i = (blockIdx.x * blockDim.x + threadIdx.x) * 8;
    int stride = gridDim.x * blockDim.x * 8;
    for (; i < total; i += stride) {
        float4v a = *(const float4v*)(feat + i);
        float4v b = *(const float4v*)(feat + i + 4);
        union { __half2 h2[4]; uint4 u; } o;
        o.h2[0] = __floats2half2_rn(a.x, a.y);
        o.h2[1] = __floats2half2_rn(a.z, a.w);
        o.h2[2] = __floats2half2_rn(b.x, b.y);
        o.h2[3] = __floats2half2_rn(b.z, b.w);
        *(uint4*)(feat16 + i) = o.u;
    }
}

__global__ void k_prep(const float* __restrict__ Wih,
                       const float* __restrict__ Whh,
                       const float* __restrict__ bih,
                       const float* __restrict__ bhh,
                       short* __restrict__ Wch, short* __restrict__ Wcl,
                       float* __restrict__ bsum) {
    int idx = blockIdx.x * blockDim.x + threadIdx.x;
    if (idx >= G4 * K2) return;
    int r = idx >> 9, cc = idx & (K2 - 1);
    float v = Wih[idx];
    if (cc < D) v += Whh[r * D + cc];
    short hi = f2bf(v);
    Wch[idx] = hi;
    Wcl[idx] = f2bf(v - bfs2f(hi));
    if (idx < G4) bsum[idx] = bih[idx] + bhh[idx];
}

__global__ __launch_bounds__(256) void k_gemm_lstm(
        const short* __restrict__ Xh, const short* __restrict__ Xl,
        const short* __restrict__ Wch, const short* __restrict__ Wcl,
        const float* __restrict__ bsum,
        float* __restrict__ c, float* __restrict__ h) {
    int wave = threadIdx.x >> 6, lane = threadIdx.x & 63;
    int row = lane & 15, quad = lane >> 4;
    int m0 = blockIdx.x * 16;
    int jbase = blockIdx.y * 64 + wave * 16;
    const short* pah = Xh  + (size_t)(m0 + row) * K2 + quad * 8;
    const short* pal = Xl  + (size_t)(m0 + row) * K2 + quad * 8;
    const short* pbh = Wch + (size_t)(jbase + row) * K2 + quad * 8;
    const short* pbl = Wcl + (size_t)(jbase + row) * K2 + quad * 8;
    float4v acc0 = {0,0,0,0}, acc1 = {0,0,0,0}, acc2 = {0,0,0,0}, acc3 = {0,0,0,0};
#pragma unroll
    for (int k = 0; k < K2; k += 32) {
        short8 ahi = *(const short8*)(pah + k);
        short8 alo = *(const short8*)(pal + k);
#define GATE_MFMA(ACC, OFF)                                                        \
        {                                                                          \
            short8 bh = *(const short8*)(pbh + (size_t)(OFF) * K2 + k);            \
            short8 bl = *(const short8*)(pbl + (size_t)(OFF) * K2 + k);            \
            ACC = __builtin_amdgcn_mfma_f32_16x16x32_bf16(ahi, bh, ACC, 0, 0, 0);  \
            ACC = __builtin_amdgcn_mfma_f32_16x16x32_bf16(alo, bh, ACC, 0, 0, 0);  \
            ACC = __builtin_amdgcn_mfma_f32_16x16x32_bf16(ahi, bl, ACC, 0, 0, 0);  \
        }
        GATE_MFMA(acc0, 0)
        GATE_MFMA(acc1, 256)
        GATE_MFMA(acc2, 512)
        GATE_MFMA(acc3, 768)
#undef GATE_MFMA
    }
    int j = jbase + (lane & 15);
    float bi = bsum[j], bf_ = bsum[j + 256], bg = bsum[j + 512], bo = bsum[j + 768];
#pragma unroll
    for (int i = 0; i < 4; i++) {
        int m = m0 + quad * 4 + i;
        size_t ix = (size_t)m * D + j;
        float gi = acc0[i] + bi, gf = acc1[i] + bf_, gg = acc2[i] + bg, go = acc3[i] + bo;
        float si = 1.f / (1.f + __expf(-gi));
        float sf = 1.f / (1.f + __expf(-gf));
        float so = 1.f / (1.f + __expf(-go));
        float cn = sf * c[ix] + si * tanhf(gg);
        float hn = so * tanhf(cn);
        c[ix] = cn;
        h[ix] = hn;
    }
}

__global__ __launch_bounds__(256) void k_attn(const __half* __restrict__ feat16,
                                              const int* __restrict__ start,
                                              const float* __restrict__ h,
                                              float* __restrict__ X,
                                              short* __restrict__ Xh,
                                              short* __restrict__ Xl, int N) {
    __shared__ float accs[4 * D];
    __shared__ float ms[4], ls[4];
    int g = blockIdx.x;
    int t = threadIdx.x;
    int lane = t & 63, wave = t >> 6;
    float hv = h[(size_t)g * D + t];
    {
        size_t ox = (size_t)g * K2 + t;
        X[ox] = hv;
        short hi = f2bf(hv);
        Xh[ox] = hi;
        Xl[ox] = f2bf(hv - bfs2f(hi));
    }
    int s = start[g], e = start[g + 1];
    s = max(0, min(s, N)); e = max(s, min(e, N));
    int cnt = e - s;
    if (cnt <= 0) {
        size_t ox = (size_t)g * K2 + D + t;
        X[ox] = 0.f; Xh[ox] = 0; Xl[ox] = 0;
        return;
    }
    const float NEG = -3.0e38f;
    float4v q = *(const float4v*)(h + (size_t)g * D + lane * 4);
    float m = NEG, l = 0.f;
    float4v acc = {0.f, 0.f, 0.f, 0.f};

    for (int n0 = wave * 4; n0 < cnt; n0 += 16) {
        uint2 raw[4];
#pragma unroll
        for (int r = 0; r < 4; r++) {
            int idx = n0 + r;
            int ci = (idx < cnt) ? (s + idx) : s;
            raw[r] = *((const uint2*)(feat16 + (size_t)ci * D) + lane);
        }
        float4v rows[4];
        float ev[4];
#pragma unroll
        for (int r = 0; r < 4; r++) {
            union { uint2 u; __half2 h2[2]; } cv; cv.u = raw[r];
            float2 f01 = __half22float2(cv.h2[0]);
            float2 f23 = __half22float2(cv.h2[1]);
            rows[r].x = f01.x; rows[r].y = f01.y; rows[r].z = f23.x; rows[r].w = f23.y;
            ev[r] = rows[r].x * q.x + rows[r].y * q.y + rows[r].z * q.z + rows[r].w * q.w;
        }
#pragma unroll
        for (int r = 0; r < 4; r++) ev[r] = wave_sum64(ev[r]);
        float mnew = m;
#pragma unroll
        for (int r = 0; r < 4; r++) {
            if (n0 + r >= cnt) ev[r] = NEG;
            mnew = fmaxf(mnew, ev[r]);
        }
        float alpha = __expf(m - mnew);
        float w[4];
        float wsum = 0.f;
#pragma unroll
        for (int r = 0; r < 4; r++) {
            w[r] = (n0 + r < cnt) ? __expf(ev[r] - mnew) : 0.f;
            wsum += w[r];
        }
        l = l * alpha + wsum;
        acc.x *= alpha; acc.y *= alpha; acc.z *= alpha; acc.w *= alpha;
#pragma unroll
        for (int r = 0; r < 4; r++) {
            acc.x += w[r] * rows[r].x;
            acc.y += w[r] * rows[r].y;
            acc.z += w[r] * rows[r].z;
            acc.w += w[r] * rows[r].w;
        }
        m = mnew;
    }

    *((float4v*)(accs + wave * D + lane * 4)) = acc;
    if (lane == 0) { ms[wave] = m; ls[wave] = l; }
    __syncthreads();
    float mt = fmaxf(fmaxf(ms[0], ms[1]), fmaxf(ms[2], ms[3]));
    float s0 = __expf(ms[0] - mt), s1 = __expf(ms[1] - mt);
    float s2 = __expf(ms[2] - mt), s3 = __expf(ms[3] - mt);
    float lt = ls[0] * s0 + ls[1] * s1 + ls[2] * s2 + ls[3] * s3;
    float val = (accs[t] * s0 + accs[D + t] * s1
               + accs[2 * D + t] * s2 + accs[3 * D + t] * s3) / lt;
    size_t ox = (size_t)g * K2 + D + t;
    X[ox] = val;
    short hi = f2bf(val);
    Xh[ox] = hi;
    Xl[ox] = f2bf(val - bfs2f(hi));
}

extern "C" void kernel_launch(void* const* d_in, const int* in_sizes, int n_in,
                              void* d_out, int out_size, void* d_ws, size_t ws_size,
                              hipStream_t stream) {
    const float* feat = (const float*)d_in[0];
    const float* Wih  = (const float*)d_in[1];
    const float* Whh  = (const float*)d_in[2];
    const float* bih  = (const float*)d_in[3];
    const float* bhh  = (const float*)d_in[4];
    const int*   seg  = (const int*)d_in[5];
    int N = in_sizes[5];
    const int B = B_;

    char* ws = (char*)d_ws;
    size_t szC = (size_t)B * D * sizeof(float);          // 1 MB
    float* c   = (float*)ws;
    float* h   = (float*)(ws + szC);
    short* Xh  = (short*)(ws + 2 * szC);
    short* Xl  = (short*)(ws + 2 * szC + (size_t)B * K2 * sizeof(short));
    short* Wch = (short*)(ws + 2 * szC + 2 * (size_t)B * K2 * sizeof(short));
    short* Wcl = (short*)((char*)Wch + (size_t)G4 * K2 * sizeof(short));
    float* bsum = (float*)((char*)Wcl + (size_t)G4 * K2 * sizeof(short));
    int*   start = (int*)((char*)bsum + (size_t)G4 * sizeof(float));
    __half* feat16 = (__half*)(ws + (size_t)16 * 1024 * 1024);

    float* X = (float*)d_out;      // q_star [B, 2D] fp32

    void* args[] = {
        (void*)&feat, (void*)&feat16, (void*)&Wih, (void*)&Whh,
        (void*)&bih,  (void*)&bhh,    (void*)&seg, (void*)&N,
        (void*)&Wch,  (void*)&Wcl,    (void*)&bsum, (void*)&start,
        (void*)&Xh,   (void*)&Xl,     (void*)&c,    (void*)&h, (void*)&X
    };
    hipError_t err = hipLaunchCooperativeKernel((const void*)k_fused,
                                                dim3(NBLK), dim3(NTHR),
                                                args, 0, stream);
    if (err != hipSuccess) {
        // proven multi-kernel fallback (round-0 pipeline)
        const int total = N * D;
        hipMemsetAsync(ws, 0, 2 * szC + 2 * (size_t)B * K2 * sizeof(short), stream);
        k_cvt<<<8192, 256, 0, stream>>>(feat, feat16, total);
        k_prep<<<(G4 * K2 + 255) / 256, 256, 0, stream>>>(Wih, Whh, bih, bhh, Wch, Wcl, bsum);
        k_bounds<<<(B + 1 + 255) / 256, 256, 0, stream>>>(seg, N, B, start);
        for (int it = 0; it < 6; it++) {
            k_gemm_lstm<<<dim3(B / 16, 4), 256, 0, stream>>>(Xh, Xl, Wch, Wcl, bsum, c, h);
            k_attn<<<B, 256, 0, stream>>>(feat16, start, h, X, Xh, Xl, N);
        }
    }
}

// Round 5
// 546.020 us; speedup vs baseline: 2.5326x; 2.5326x over previous
//
#include <hip/hip_runtime.h>
#include <hip/hip_bf16.h>
#include <hip/hip_fp16.h>
#include <stdint.h>

#define D    256   // hidden dim
#define K2   512   // 2*D (GEMM K, q_star width)
#define G4   1024  // 4*D (gate count)
#define B_   1024  // batch (graphs)

typedef __attribute__((ext_vector_type(8))) short  short8;
typedef __attribute__((ext_vector_type(4))) float  float4v;

__device__ inline short f2bf(float v) {
    __hip_bfloat16 b = __float2bfloat16(v);
    union { __hip_bfloat16 b; unsigned short u; } cv; cv.b = b;
    return (short)cv.u;
}
__device__ inline float bfs2f(short s) {
    union { unsigned int i; float f; } v;
    v.i = ((unsigned int)(unsigned short)s) << 16;
    return v.f;
}

// ---- wave64 sum via DPP (VALU pipe only — no ds_bpermute) -------------------
__device__ inline float wave_sum64(float x) {
    union { float f; int i; } c, t;
#define DPP_ADD(CTRL, RM)                                                     \
    c.f = x;                                                                  \
    t.i = __builtin_amdgcn_update_dpp(0, c.i, (CTRL), (RM), 0xf, true);       \
    x += t.f;
    DPP_ADD(0x111, 0xf)   // row_shr:1
    DPP_ADD(0x112, 0xf)   // row_shr:2
    DPP_ADD(0x114, 0xf)   // row_shr:4
    DPP_ADD(0x118, 0xf)   // row_shr:8
    DPP_ADD(0x142, 0xa)   // row_bcast:15 -> rows 1,3
    DPP_ADD(0x143, 0xc)   // row_bcast:31 -> rows 2,3
#undef DPP_ADD
    union { float f; int i; } r; r.f = x;
    r.i = __builtin_amdgcn_readlane(r.i, 63);
    return r.f;
}

// ---- setup: weight prep + state zeroing + per-graph bounds (one kernel) -----
// grid 2048x256 = G4*K2 threads exactly.
__global__ __launch_bounds__(256) void k_prep2(
        const float* __restrict__ Wih, const float* __restrict__ Whh,
        const float* __restrict__ bih, const float* __restrict__ bhh,
        const int* __restrict__ seg, int N,
        short* __restrict__ Wch, short* __restrict__ Wcl,
        float* __restrict__ bsum, int* __restrict__ start,
        float* __restrict__ c, float* __restrict__ h,
        short* __restrict__ Xh, short* __restrict__ Xl) {
    int idx = blockIdx.x * blockDim.x + threadIdx.x;   // 0 .. G4*K2-1
    // zero LSTM state (B*D floats each) and q_star bf16 buffers (B*K2 shorts)
    if (idx < B_ * D) { c[idx] = 0.f; h[idx] = 0.f; }
    Xh[idx] = 0; Xl[idx] = 0;
    // per-graph boundaries: start[g] = first node with seg >= g
    if (idx <= B_) {
        int lo = 0, hi = N;
        while (lo < hi) { int mid = (lo + hi) >> 1; if (seg[mid] < idx) lo = mid + 1; else hi = mid; }
        start[idx] = lo;
    }
    // Wc = [Wih[:, :D] + Whh | Wih[:, D:2D]] split into bf16 hi+lo
    int r = idx >> 9, cc = idx & (K2 - 1);
    float v = Wih[idx];
    if (cc < D) v += Whh[r * D + cc];
    short hi = f2bf(v);
    Wch[idx] = hi;
    Wcl[idx] = f2bf(v - bfs2f(hi));
    if (idx < G4) bsum[idx] = bih[idx] + bhh[idx];
}

// ---- fused gates GEMM + LSTM pointwise (round-0 proven shape) ---------------
// grid (64,4), 4 waves/block; wave w covers 16 cols of each of the 4 gates
// (4 independent accumulators -> MFMA ILP). A.B ~ Ah.Bh + Al.Bh + Ah.Bl.
__global__ __launch_bounds__(256) void k_gemm_lstm(
        const short* __restrict__ Xh, const short* __restrict__ Xl,
        const short* __restrict__ Wch, const short* __restrict__ Wcl,
        const float* __restrict__ bsum,
        float* __restrict__ c, float* __restrict__ h) {
    int wave = threadIdx.x >> 6, lane = threadIdx.x & 63;
    int row = lane & 15, quad = lane >> 4;
    int m0 = blockIdx.x * 16;
    int jbase = blockIdx.y * 64 + wave * 16;
    const short* pah = Xh  + (size_t)(m0 + row) * K2 + quad * 8;
    const short* pal = Xl  + (size_t)(m0 + row) * K2 + quad * 8;
    const short* pbh = Wch + (size_t)(jbase + row) * K2 + quad * 8;
    const short* pbl = Wcl + (size_t)(jbase + row) * K2 + quad * 8;
    float4v acc0 = {0,0,0,0}, acc1 = {0,0,0,0}, acc2 = {0,0,0,0}, acc3 = {0,0,0,0};
#pragma unroll
    for (int k = 0; k < K2; k += 32) {
        short8 ahi = *(const short8*)(pah + k);
        short8 alo = *(const short8*)(pal + k);
#define GATE_MFMA(ACC, OFF)                                                        \
        {                                                                          \
            short8 bh = *(const short8*)(pbh + (size_t)(OFF) * K2 + k);            \
            short8 bl = *(const short8*)(pbl + (size_t)(OFF) * K2 + k);            \
            ACC = __builtin_amdgcn_mfma_f32_16x16x32_bf16(ahi, bh, ACC, 0, 0, 0);  \
            ACC = __builtin_amdgcn_mfma_f32_16x16x32_bf16(alo, bh, ACC, 0, 0, 0);  \
            ACC = __builtin_amdgcn_mfma_f32_16x16x32_bf16(ahi, bl, ACC, 0, 0, 0);  \
        }
        GATE_MFMA(acc0, 0)
        GATE_MFMA(acc1, 256)
        GATE_MFMA(acc2, 512)
        GATE_MFMA(acc3, 768)
#undef GATE_MFMA
    }
    // C/D layout: col = lane&15 (N dim = j), row = quad*4 + i (M dim = batch)
    int j = jbase + (lane & 15);
    float bi = bsum[j], bf_ = bsum[j + 256], bg = bsum[j + 512], bo = bsum[j + 768];
#pragma unroll
    for (int i = 0; i < 4; i++) {
        int m = m0 + quad * 4 + i;
        size_t ix = (size_t)m * D + j;
        float gi = acc0[i] + bi, gf = acc1[i] + bf_, gg = acc2[i] + bg, go = acc3[i] + bo;
        float si = 1.f / (1.f + __expf(-gi));
        float sf = 1.f / (1.f + __expf(-gf));
        float so = 1.f / (1.f + __expf(-go));
        float cn = sf * c[ix] + si * tanhf(gg);
        float hn = so * tanhf(cn);
        c[ix] = cn;
        h[ix] = hn;
    }
}

// ---- attention, single pass, online softmax, DPP reduce, prefetch-pipelined -
// Block g = graph g. Wave w handles rows w*4.., stride 16, 4 rows/step.
// Lane owns dims lane*4..+3. Next step's loads are issued before the current
// step's compute (manual software pipeline -> latency hidden under VALU work).
// FIRST=true: reads fp32 feat, writes fp16 copy on the fly (fused cvt).
template <bool FIRST>
__global__ __launch_bounds__(256) void k_attn_t(const float* __restrict__ feat32,
                                                __half* __restrict__ feat16,
                                                const int* __restrict__ start,
                                                const float* __restrict__ h,
                                                float* __restrict__ X,
                                                short* __restrict__ Xh,
                                                short* __restrict__ Xl, int N) {
    __shared__ float accs[4 * D];
    __shared__ float ms[4], ls[4];
    int g = blockIdx.x;
    int t = threadIdx.x;
    int lane = t & 63, wave = t >> 6;
    // publish h into q_star row g (block g owns row g -> race-free)
    float hv = h[(size_t)g * D + t];
    {
        size_t ox = (size_t)g * K2 + t;
        X[ox] = hv;
        short hi = f2bf(hv);
        Xh[ox] = hi;
        Xl[ox] = f2bf(hv - bfs2f(hi));
    }
    int s = start[g], e = start[g + 1];
    s = max(0, min(s, N)); e = max(s, min(e, N));
    int cnt = e - s;
    if (cnt <= 0) {
        size_t ox = (size_t)g * K2 + D + t;
        X[ox] = 0.f; Xh[ox] = 0; Xl[ox] = 0;
        return;
    }
    const float NEG = -3.0e38f;
    float4v q = *(const float4v*)(h + (size_t)g * D + lane * 4);
    float m = NEG, l = 0.f;
    float4v acc = {0.f, 0.f, 0.f, 0.f};

    float4v rows[4];   // current tile (fp32 path)
    uint2   raw[4];    // current tile (fp16 path)
    int n0 = wave * 4;
    if (n0 < cnt) {
        // prologue: load first tile
#pragma unroll
        for (int r = 0; r < 4; r++) {
            int idx = n0 + r;
            int ci = (idx < cnt) ? (s + idx) : s;     // clamp: no OOB read
            if (FIRST) rows[r] = *((const float4v*)(feat32 + (size_t)ci * D) + lane);
            else       raw[r]  = *((const uint2*)(feat16 + (size_t)ci * D) + lane);
        }
        for (; n0 < cnt; n0 += 16) {
            // ---- prefetch next tile (clamp-safe even past the end) ----------
            float4v rowsn[4];
            uint2   rawn[4];
            int n1 = n0 + 16;
#pragma unroll
            for (int r = 0; r < 4; r++) {
                int idx = n1 + r;
                int ci = (idx < cnt) ? (s + idx) : s;
                if (FIRST) rowsn[r] = *((const float4v*)(feat32 + (size_t)ci * D) + lane);
                else       rawn[r]  = *((const uint2*)(feat16 + (size_t)ci * D) + lane);
            }
            // ---- decode current / fp16 side-effect write --------------------
            if (FIRST) {
#pragma unroll
                for (int r = 0; r < 4; r++) {
                    int idx = n0 + r;
                    if (idx < cnt) {
                        union { uint2 u; __half2 h2[2]; } cv;
                        cv.h2[0] = __floats2half2_rn(rows[r].x, rows[r].y);
                        cv.h2[1] = __floats2half2_rn(rows[r].z, rows[r].w);
                        *((uint2*)(feat16 + (size_t)(s + idx) * D) + lane) = cv.u;
                    }
                }
            } else {
#pragma unroll
                for (int r = 0; r < 4; r++) {
                    union { uint2 u; __half2 h2[2]; } cv; cv.u = raw[r];
                    float2 f01 = __half22float2(cv.h2[0]);
                    float2 f23 = __half22float2(cv.h2[1]);
                    rows[r].x = f01.x; rows[r].y = f01.y;
                    rows[r].z = f23.x; rows[r].w = f23.y;
                }
            }
            // ---- online softmax step ----------------------------------------
            float ev[4];
#pragma unroll
            for (int r = 0; r < 4; r++)
                ev[r] = rows[r].x * q.x + rows[r].y * q.y
                      + rows[r].z * q.z + rows[r].w * q.w;
#pragma unroll
            for (int r = 0; r < 4; r++) ev[r] = wave_sum64(ev[r]);
            float mnew = m;
#pragma unroll
            for (int r = 0; r < 4; r++) {
                if (n0 + r >= cnt) ev[r] = NEG;
                mnew = fmaxf(mnew, ev[r]);
            }
            float alpha = __expf(m - mnew);
            float w[4];
            float wsum = 0.f;
#pragma unroll
            for (int r = 0; r < 4; r++) {
                w[r] = (n0 + r < cnt) ? __expf(ev[r] - mnew) : 0.f;
                wsum += w[r];
            }
            l = l * alpha + wsum;
            acc.x *= alpha; acc.y *= alpha; acc.z *= alpha; acc.w *= alpha;
#pragma unroll
            for (int r = 0; r < 4; r++) {
                acc.x += w[r] * rows[r].x;
                acc.y += w[r] * rows[r].y;
                acc.z += w[r] * rows[r].z;
                acc.w += w[r] * rows[r].w;
            }
            m = mnew;
            // ---- rotate pipeline --------------------------------------------
#pragma unroll
            for (int r = 0; r < 4; r++) {
                if (FIRST) rows[r] = rowsn[r];
                else       raw[r]  = rawn[r];
            }
        }
    }

    // merge 4 waves via LDS (one-time)
    *((float4v*)(accs + wave * D + lane * 4)) = acc;
    if (lane == 0) { ms[wave] = m; ls[wave] = l; }
    __syncthreads();
    float mt = fmaxf(fmaxf(ms[0], ms[1]), fmaxf(ms[2], ms[3]));
    float s0 = __expf(ms[0] - mt), s1 = __expf(ms[1] - mt);
    float s2 = __expf(ms[2] - mt), s3 = __expf(ms[3] - mt);
    float lt = ls[0] * s0 + ls[1] * s1 + ls[2] * s2 + ls[3] * s3;
    float val = (accs[t] * s0 + accs[D + t] * s1
               + accs[2 * D + t] * s2 + accs[3 * D + t] * s3) / lt;
    size_t ox = (size_t)g * K2 + D + t;
    X[ox] = val;
    short hi = f2bf(val);
    Xh[ox] = hi;
    Xl[ox] = f2bf(val - bfs2f(hi));
}

extern "C" void kernel_launch(void* const* d_in, const int* in_sizes, int n_in,
                              void* d_out, int out_size, void* d_ws, size_t ws_size,
                              hipStream_t stream) {
    const float* feat = (const float*)d_in[0];
    const float* Wih  = (const float*)d_in[1];
    const float* Whh  = (const float*)d_in[2];
    const float* bih  = (const float*)d_in[3];
    const float* bhh  = (const float*)d_in[4];
    const int*   seg  = (const int*)d_in[5];
    const int N = in_sizes[5];
    const int B = B_;

    // ws: [c 1MB | h 1MB | Xh 1MB | Xl 1MB | Wch 1MB | Wcl 1MB | bsum | start]
    // then feat16 at 16MB offset (102.4 MB)
    char* ws = (char*)d_ws;
    size_t szC = (size_t)B * D * sizeof(float);            // 1 MB
    float* c   = (float*)ws;
    float* h   = (float*)(ws + szC);
    short* Xh  = (short*)(ws + 2 * szC);
    short* Xl  = (short*)(ws + 2 * szC + (size_t)B * K2 * sizeof(short));
    short* Wch = (short*)(ws + 2 * szC + 2 * (size_t)B * K2 * sizeof(short));
    short* Wcl = (short*)((char*)Wch + (size_t)G4 * K2 * sizeof(short));
    float* bsum = (float*)((char*)Wcl + (size_t)G4 * K2 * sizeof(short));
    int*   start = (int*)((char*)bsum + (size_t)G4 * sizeof(float));
    __half* feat16 = (__half*)(ws + (size_t)16 * 1024 * 1024);

    float* X = (float*)d_out;      // q_star [B, 2D] fp32

    // one setup kernel: weight prep + state zeroing + bounds (G4*K2 threads)
    k_prep2<<<G4 * K2 / 256, 256, 0, stream>>>(Wih, Whh, bih, bhh, seg, N,
                                               Wch, Wcl, bsum, start, c, h, Xh, Xl);

    for (int it = 0; it < 6; it++) {
        k_gemm_lstm<<<dim3(B / 16, 4), 256, 0, stream>>>(Xh, Xl, Wch, Wcl, bsum, c, h);
        if (it == 0)
            k_attn_t<true ><<<B, 256, 0, stream>>>(feat, feat16, start, h, X, Xh, Xl, N);
        else
            k_attn_t<false><<<B, 256, 0, stream>>>(feat, feat16, start, h, X, Xh, Xl, N);
    }
}